// Round 3
// baseline (1734.690 us; speedup 1.0000x reference)
//
#include <hip/hip_runtime.h>

// ---------------------------------------------------------------------------
// LearnableCurvGCN: 2-layer GCN with learnable per-edge weights from a tiny
// curvature MLP. All fp32.
//
// Pipeline:
//   1. edge MLP -> ew[e];      atomicAdd(deg[dst], ew)
//   2. dis[n] = rsqrt(deg[n] + 1)                      (in-place over deg)
//   3. norm[e] = dis[src]*ew[e]*dis[dst]               (in-place over ew)
//   4. xw1 = x @ W1                                    (fp32 GEMM)
//   5. agg1[dst] += norm * xw1[src]                    (atomic scatter)
//   6. h1 = relu(agg1 + dis^2*xw1 + b1)                (in-place over agg1)
//   7. xw2 = h1 @ W2                                   (aliases xw1 buffer)
//   8. out[dst] += norm * xw2[src]                     (atomic scatter -> d_out)
//   9. out += dis^2*xw2 + b2
// ---------------------------------------------------------------------------

constexpr int N_NODES = 100000;
constexpr int N_EDGES = 1600000;
constexpr int IN_DIM  = 128;
constexpr int HID_DIM = 128;
constexpr int OUT_DIM = 64;

// --- 1. per-edge curvature MLP + weighted degree ---------------------------
__global__ void k_edge_mlp(const float* __restrict__ curv,
                           const int*   __restrict__ dst,
                           const float* __restrict__ mw1,
                           const float* __restrict__ mb1,
                           const float* __restrict__ mw2,
                           const float* __restrict__ mb2,
                           float* __restrict__ ew,
                           float* __restrict__ deg)
{
    int e = blockIdx.x * blockDim.x + threadIdx.x;
    if (e >= N_EDGES) return;
    float c = curv[e];
    float z = mb2[0];
#pragma unroll
    for (int i = 0; i < 16; ++i) {
        float h = fmaf(c, mw1[i], mb1[i]);
        h = fmaxf(h, 0.0f);
        z = fmaf(h, mw2[i], z);
    }
    float s = 1.0f / (1.0f + __expf(-z));
    float w = fmaf(0.9f, s, 0.1f);
    ew[e] = w;
    atomicAdd(&deg[dst[e]], w);
}

// --- 2. dis = rsqrt(deg + 1)  (deg >= 0, so deg+1 >= 1 > 0 always) ---------
__global__ void k_dis(float* __restrict__ deg_dis)
{
    int n = blockIdx.x * blockDim.x + threadIdx.x;
    if (n >= N_NODES) return;
    deg_dis[n] = rsqrtf(deg_dis[n] + 1.0f);
}

// --- 3. norm[e] = dis[src]*ew[e]*dis[dst]  (in place over ew) ---------------
__global__ void k_norm(const int*   __restrict__ src,
                       const int*   __restrict__ dst,
                       const float* __restrict__ dis,
                       float*       __restrict__ ew_norm)
{
    int e = blockIdx.x * blockDim.x + threadIdx.x;
    if (e >= N_EDGES) return;
    ew_norm[e] = dis[src[e]] * ew_norm[e] * dis[dst[e]];
}

// --- 4/7. fp32 GEMM: C[N,KOUT] = A[N,KIN] @ W[KIN,KOUT] ---------------------
// Thread per output element. Across a wave, c is consecutive -> W reads
// coalesced; a[k] is the same address for the whole row-group -> broadcast.
template <int KIN, int KOUT>
__global__ void k_gemm(const float* __restrict__ A,
                       const float* __restrict__ W,
                       float* __restrict__ C)
{
    int idx = blockIdx.x * blockDim.x + threadIdx.x;   // < N_NODES*KOUT < 2^31
    if (idx >= N_NODES * KOUT) return;
    int r = idx / KOUT;
    int c = idx - r * KOUT;
    const float* a = A + (long long)r * KIN;
    float acc = 0.0f;
#pragma unroll 8
    for (int k = 0; k < KIN; ++k)
        acc = fmaf(a[k], W[k * KOUT + c], acc);
    C[idx] = acc;
}

// --- 5/8. scatter: agg[dst*DIM+d] += norm[e] * xw[src*DIM+d] ----------------
template <int DIM>
__global__ void k_scatter(const int*   __restrict__ src,
                          const int*   __restrict__ dst,
                          const float* __restrict__ norm,
                          const float* __restrict__ xw,
                          float*       __restrict__ agg)
{
    long long t = (long long)blockIdx.x * blockDim.x + threadIdx.x;
    if (t >= (long long)N_EDGES * DIM) return;
    int e = (int)(t / DIM);
    int d = (int)(t - (long long)e * DIM);
    float v = norm[e] * xw[(long long)src[e] * DIM + d];
    atomicAdd(&agg[(long long)dst[e] * DIM + d], v);
}

// --- 6/9. finalize: out = agg + dis^2 * xw + b, optional relu ---------------
template <int DIM, bool RELU>
__global__ void k_final(const float* __restrict__ xw,
                        const float* __restrict__ dis,
                        const float* __restrict__ b,
                        float* __restrict__ agg_out)
{
    int idx = blockIdx.x * blockDim.x + threadIdx.x;
    if (idx >= N_NODES * DIM) return;
    int r = idx / DIM;
    int d = idx - r * DIM;
    float s = dis[r];
    float v = agg_out[idx] + s * s * xw[idx] + b[d];
    if (RELU) v = fmaxf(v, 0.0f);
    agg_out[idx] = v;
}

extern "C" void kernel_launch(void* const* d_in, const int* in_sizes, int n_in,
                              void* d_out, int out_size, void* d_ws, size_t ws_size,
                              hipStream_t stream)
{
    const float* x    = (const float*)d_in[0];
    const int*   eidx = (const int*)  d_in[1];   // [2, N_EDGES] int32
    const float* curv = (const float*)d_in[2];   // [N_EDGES, 1]
    const float* W1   = (const float*)d_in[3];
    const float* b1   = (const float*)d_in[4];
    const float* W2   = (const float*)d_in[5];
    const float* b2   = (const float*)d_in[6];
    const float* mw1  = (const float*)d_in[7];
    const float* mb1  = (const float*)d_in[8];
    const float* mw2  = (const float*)d_in[9];
    const float* mb2  = (const float*)d_in[10];

    const int* src = eidx;
    const int* dst = eidx + N_EDGES;
    float* out = (float*)d_out;

    // --- workspace carve-out (~109 MB) ---
    char*  ws  = (char*)d_ws;
    size_t off = 0;
    auto alloc = [&](size_t bytes) -> void* {
        void* p = ws + off;
        off += (bytes + 255) & ~(size_t)255;
        return p;
    };
    float* ew   = (float*)alloc(sizeof(float) * N_EDGES);                       // -> norm (in place)
    float* deg  = (float*)alloc(sizeof(float) * N_NODES);                       // -> dis (in place)
    float* xw1  = (float*)alloc(sizeof(float) * (size_t)N_NODES * HID_DIM);     // -> xw2 aliases
    float* agg1 = (float*)alloc(sizeof(float) * (size_t)N_NODES * HID_DIM);     // -> h1 (in place)
    float* xw2  = xw1;   // xw1 dead after finalize1; layer-2 product fits inside

    // zero the accumulators every call (harness poisons once, never re-poisons)
    hipMemsetAsync(deg,  0, sizeof(float) * N_NODES, stream);
    hipMemsetAsync(agg1, 0, sizeof(float) * (size_t)N_NODES * HID_DIM, stream);
    hipMemsetAsync(out,  0, sizeof(float) * (size_t)N_NODES * OUT_DIM, stream);

    const int B = 256;
    auto cdiv = [](long long a, long long b) { return (int)((a + b - 1) / b); };

    // 1-3: edge weights, degrees, norms
    k_edge_mlp<<<cdiv(N_EDGES, B), B, 0, stream>>>(curv, dst, mw1, mb1, mw2, mb2, ew, deg);
    k_dis     <<<cdiv(N_NODES, B), B, 0, stream>>>(deg);
    k_norm    <<<cdiv(N_EDGES, B), B, 0, stream>>>(src, dst, deg, ew);

    // layer 1
    k_gemm<IN_DIM, HID_DIM><<<cdiv((long long)N_NODES * HID_DIM, B), B, 0, stream>>>(x, W1, xw1);
    k_scatter<HID_DIM>     <<<cdiv((long long)N_EDGES * HID_DIM, B), B, 0, stream>>>(src, dst, ew, xw1, agg1);
    k_final<HID_DIM, true> <<<cdiv((long long)N_NODES * HID_DIM, B), B, 0, stream>>>(xw1, deg, b1, agg1);

    // layer 2 (h1 lives in agg1; xw2 aliases xw1's storage)
    k_gemm<HID_DIM, OUT_DIM><<<cdiv((long long)N_NODES * OUT_DIM, B), B, 0, stream>>>(agg1, W2, xw2);
    k_scatter<OUT_DIM>      <<<cdiv((long long)N_EDGES * OUT_DIM, B), B, 0, stream>>>(src, dst, ew, xw2, out);
    k_final<OUT_DIM, false> <<<cdiv((long long)N_NODES * OUT_DIM, B), B, 0, stream>>>(xw2, deg, b2, out);
}

// Round 4
// 871.480 us; speedup vs baseline: 1.9905x; 1.9905x over previous
//
#include <hip/hip_runtime.h>

// ---------------------------------------------------------------------------
// LearnableCurvGCN, round 3: kill the atomic scatters.
//
// R2 counters: the two k_scatter dispatches were ~1030us of 1735us, at 23%
// HBM BW / 15% VALUBusy, with WRITE_SIZE == 4B * n_atomics (no coalescing) —
// atomic-RMW bound. Replace scatter with CSR-by-dst gather:
//
//   1. k_edge_deg : per-edge MLP -> w;  atomicAdd(deg[dst],w), cnt[dst]++
//   2. k_dis      : dis = rsqrt(deg+1)            (in place)
//   3. k_scan     : rp = exclusive_scan(cnt)      (single block, in place)
//   4. k_reorder  : bucket edges by dst; store (srcp, normp) reordered
//                   (norm = dis[src]*w*dis[dst], MLP recomputed — cheap)
//   5. k_gemm     : xw1 = x @ W1      (2 rows x float4 cols per thread)
//   6. k_gather   : h1[n] = relu(sum_{e in CSR[n]} normp*xw1[srcp]
//                              + dis[n]^2*xw1[n] + b1)   [fused finalize]
//   7. k_gemm     : xw2 = h1 @ W2
//   8. k_gather   : out[n] = sum + dis^2*xw2[n] + b2     [writes d_out once]
//
// No big memsets, no k_final passes, zero atomics in the hot path.
// ---------------------------------------------------------------------------

constexpr int N_NODES = 100000;
constexpr int N_EDGES = 1600000;
constexpr int IN_DIM  = 128;
constexpr int HID_DIM = 128;
constexpr int OUT_DIM = 64;

// --- tiny curvature MLP (16-wide), shared by k_edge_deg and k_reorder -------
__device__ __forceinline__ float edge_weight_mlp(float c,
                                                 const float* __restrict__ mw1,
                                                 const float* __restrict__ mb1,
                                                 const float* __restrict__ mw2,
                                                 const float* __restrict__ mb2)
{
    float z = mb2[0];
#pragma unroll
    for (int i = 0; i < 16; ++i) {
        float h = fmaf(c, mw1[i], mb1[i]);
        h = fmaxf(h, 0.0f);
        z = fmaf(h, mw2[i], z);
    }
    float s = 1.0f / (1.0f + __expf(-z));
    return fmaf(0.9f, s, 0.1f);
}

// --- 1. per-edge weight -> weighted degree + in-degree count ----------------
__global__ void k_edge_deg(const float* __restrict__ curv,
                           const int*   __restrict__ dst,
                           const float* __restrict__ mw1,
                           const float* __restrict__ mb1,
                           const float* __restrict__ mw2,
                           const float* __restrict__ mb2,
                           float* __restrict__ deg,
                           int*   __restrict__ cnt)
{
    int e = blockIdx.x * blockDim.x + threadIdx.x;
    if (e >= N_EDGES) return;
    float w = edge_weight_mlp(curv[e], mw1, mb1, mw2, mb2);
    int t = dst[e];
    atomicAdd(&deg[t], w);
    atomicAdd(&cnt[t], 1);
}

// --- 2. dis = rsqrt(deg + 1) ------------------------------------------------
__global__ void k_dis(float* __restrict__ deg_dis)
{
    int n = blockIdx.x * blockDim.x + threadIdx.x;
    if (n >= N_NODES) return;
    deg_dis[n] = rsqrtf(deg_dis[n] + 1.0f);
}

// --- 3. exclusive scan of rp[0..N-1] in place; rp[N] = total ----------------
// Single block, 1024 threads, ~98 elements each. 400KB through one CU: ~us.
__global__ void k_scan(int* __restrict__ rp)
{
    __shared__ int part[1024];
    const int t = threadIdx.x;
    const int C = (N_NODES + 1023) / 1024;
    const int lo = t * C;
    const int hi = min(lo + C, N_NODES);
    int s = 0;
    for (int i = lo; i < hi; ++i) s += rp[i];
    part[t] = s;
    __syncthreads();
    // Hillis-Steele inclusive scan over the 1024 partials
    for (int ofs = 1; ofs < 1024; ofs <<= 1) {
        int v = (t >= ofs) ? part[t - ofs] : 0;
        __syncthreads();
        part[t] += v;
        __syncthreads();
    }
    int run = (t == 0) ? 0 : part[t - 1];
    for (int i = lo; i < hi; ++i) {
        int v = rp[i];
        rp[i] = run;            // exclusive position
        run += v;
    }
    if (lo < N_NODES && hi == N_NODES)
        rp[N_NODES] = run;      // total
}

// --- 4. bucket edges by dst: reordered (src, norm) pairs --------------------
__global__ void k_reorder(const float* __restrict__ curv,
                          const int*   __restrict__ src,
                          const int*   __restrict__ dst,
                          const float* __restrict__ mw1,
                          const float* __restrict__ mb1,
                          const float* __restrict__ mw2,
                          const float* __restrict__ mb2,
                          const float* __restrict__ dis,
                          const int*   __restrict__ rp,
                          int*   __restrict__ wcnt,
                          int*   __restrict__ srcp,
                          float* __restrict__ normp)
{
    int e = blockIdx.x * blockDim.x + threadIdx.x;
    if (e >= N_EDGES) return;
    float w = edge_weight_mlp(curv[e], mw1, mb1, mw2, mb2);
    int s = src[e], t = dst[e];
    float nm = dis[s] * w * dis[t];
    int pos = rp[t] + atomicAdd(&wcnt[t], 1);
    srcp[pos]  = s;
    normp[pos] = nm;
}

// --- 5/7. fp32 GEMM: C[N,KOUT] = A[N,KIN] @ W[KIN,KOUT] ---------------------
// 2 rows x float4 cols per thread: 8 FMA per {1 float4 W-load + 2 broadcast
// A-loads}. N_NODES divisible by rows-per-block (16 and 32), so both row
// loads are always in-bounds.
template <int KIN, int KOUT>
__global__ __launch_bounds__(256) void k_gemm(const float* __restrict__ A,
                                              const float* __restrict__ W,
                                              float* __restrict__ C)
{
    constexpr int CQ  = KOUT / 4;         // col-quads (one float4 each)
    constexpr int RPB = 2 * (256 / CQ);   // rows per block
    const int tid = threadIdx.x;
    const int cq  = tid % CQ;
    const int rpi = tid / CQ;
    const int r0  = blockIdx.x * RPB + 2 * rpi;
    if (r0 >= N_NODES) return;
    const float* a0 = A + (size_t)r0 * KIN;
    const float* a1 = a0 + KIN;
    float4 acc0 = {0.f, 0.f, 0.f, 0.f};
    float4 acc1 = {0.f, 0.f, 0.f, 0.f};
#pragma unroll 4
    for (int k = 0; k < KIN; ++k) {
        float4 w = *reinterpret_cast<const float4*>(&W[k * KOUT + 4 * cq]);
        float x0 = a0[k];
        float x1 = a1[k];
        acc0.x = fmaf(x0, w.x, acc0.x);
        acc0.y = fmaf(x0, w.y, acc0.y);
        acc0.z = fmaf(x0, w.z, acc0.z);
        acc0.w = fmaf(x0, w.w, acc0.w);
        acc1.x = fmaf(x1, w.x, acc1.x);
        acc1.y = fmaf(x1, w.y, acc1.y);
        acc1.z = fmaf(x1, w.z, acc1.z);
        acc1.w = fmaf(x1, w.w, acc1.w);
    }
    *reinterpret_cast<float4*>(&C[(size_t)r0 * KOUT + 4 * cq])       = acc0;
    *reinterpret_cast<float4*>(&C[(size_t)(r0 + 1) * KOUT + 4 * cq]) = acc1;
}

// --- 6/8. CSR gather with fused finalize ------------------------------------
// One block per node, one thread per output dim. srcp/normp reads are
// wave-uniform (cache broadcast); xw row reads are fully coalesced.
template <int DIM, bool RELU>
__global__ void k_gather(const int*   __restrict__ rp,
                         const int*   __restrict__ srcp,
                         const float* __restrict__ normp,
                         const float* __restrict__ xw,
                         const float* __restrict__ dis,
                         const float* __restrict__ bias,
                         float* __restrict__ out)
{
    const int n = blockIdx.x;
    const int d = threadIdx.x;
    const int beg = rp[n];
    const int end = rp[n + 1];
    float acc = 0.0f;
    for (int i = beg; i < end; ++i) {
        int   s  = srcp[i];
        float nm = normp[i];
        acc = fmaf(nm, xw[(size_t)s * DIM + d], acc);
    }
    float di = dis[n];
    float v  = fmaf(di * di, xw[(size_t)n * DIM + d], acc) + bias[d];
    if (RELU) v = fmaxf(v, 0.0f);
    out[(size_t)n * DIM + d] = v;
}

extern "C" void kernel_launch(void* const* d_in, const int* in_sizes, int n_in,
                              void* d_out, int out_size, void* d_ws, size_t ws_size,
                              hipStream_t stream)
{
    const float* x    = (const float*)d_in[0];
    const int*   eidx = (const int*)  d_in[1];   // [2, N_EDGES] int32
    const float* curv = (const float*)d_in[2];   // [N_EDGES, 1]
    const float* W1   = (const float*)d_in[3];
    const float* b1   = (const float*)d_in[4];
    const float* W2   = (const float*)d_in[5];
    const float* b2   = (const float*)d_in[6];
    const float* mw1  = (const float*)d_in[7];
    const float* mb1  = (const float*)d_in[8];
    const float* mw2  = (const float*)d_in[9];
    const float* mb2  = (const float*)d_in[10];

    const int* src = eidx;
    const int* dst = eidx + N_EDGES;
    float* out = (float*)d_out;

    // --- workspace carve-out (~116.5 MB) ---
    char*  ws  = (char*)d_ws;
    size_t off = 0;
    auto alloc = [&](size_t bytes) -> void* {
        void* p = ws + off;
        off += (bytes + 255) & ~(size_t)255;
        return p;
    };
    float* deg   = (float*)alloc(sizeof(float) * N_NODES);            // -> dis in place
    int*   rp    = (int*)  alloc(sizeof(int) * (N_NODES + 1));        // counts -> rowptr in place
    int*   wcnt  = (int*)  alloc(sizeof(int) * N_NODES);              // bucket write cursors
    int*   srcp  = (int*)  alloc(sizeof(int) * N_EDGES);              // reordered src
    float* normp = (float*)alloc(sizeof(float) * N_EDGES);            // reordered norm
    float* xw    = (float*)alloc(sizeof(float) * (size_t)N_NODES * HID_DIM);  // xw1, then xw2
    float* h1    = (float*)alloc(sizeof(float) * (size_t)N_NODES * HID_DIM);

    // zero the small accumulators every call (harness never re-poisons)
    hipMemsetAsync(deg,  0, sizeof(float) * N_NODES, stream);
    hipMemsetAsync(rp,   0, sizeof(int) * N_NODES, stream);
    hipMemsetAsync(wcnt, 0, sizeof(int) * N_NODES, stream);

    const int B = 256;
    auto cdiv = [](long long a, long long b) { return (int)((a + b - 1) / b); };

    // CSR build
    k_edge_deg<<<cdiv(N_EDGES, B), B, 0, stream>>>(curv, dst, mw1, mb1, mw2, mb2, deg, rp);
    k_dis     <<<cdiv(N_NODES, B), B, 0, stream>>>(deg);
    k_scan    <<<1, 1024, 0, stream>>>(rp);
    k_reorder <<<cdiv(N_EDGES, B), B, 0, stream>>>(curv, src, dst, mw1, mb1, mw2, mb2,
                                                   deg, rp, wcnt, srcp, normp);

    // layer 1: xw1 = x@W1; h1 = relu(gather + self + b1)
    k_gemm<IN_DIM, HID_DIM><<<cdiv(N_NODES, 16), 256, 0, stream>>>(x, W1, xw);
    k_gather<HID_DIM, true><<<N_NODES, HID_DIM, 0, stream>>>(rp, srcp, normp, xw, deg, b1, h1);

    // layer 2: xw2 = h1@W2 (reuses xw buffer); out = gather + self + b2
    k_gemm<HID_DIM, OUT_DIM><<<cdiv(N_NODES, 32), 256, 0, stream>>>(h1, W2, xw);
    k_gather<OUT_DIM, false><<<N_NODES, OUT_DIM, 0, stream>>>(rp, srcp, normp, xw, deg, b2, out);
}

// Round 5
// 762.666 us; speedup vs baseline: 2.2745x; 1.1427x over previous
//
#include <hip/hip_runtime.h>

// ---------------------------------------------------------------------------
// LearnableCurvGCN, round 4: attack gather latency + GEMM arithmetic density.
//
// R3 counters: k_gather<128> = 176us @ VALUBusy 8%, 34% HBM -> latency-bound
// (1 outstanding random row-load per thread). Fixes:
//   - gather: edge-loop unroll x4, 4 independent accumulators, packed int2
//     (src,norm) loads, multi-node blocks  -> 4x memory-level parallelism
//   - reorder: single 8B scattered store instead of two 4B stores
//   - gemm: 4 rows x float4 cols per thread, float4 A loads
//           -> 64 FMA per 8 vector loads
//
// Pipeline (unchanged structure):
//   1. k_edge_deg : per-edge MLP -> w;  atomicAdd(deg[dst],w), cnt[dst]++
//   2. k_dis      : dis = rsqrt(deg+1)              (in place)
//   3. k_scan     : rp = exclusive_scan(cnt)        (single block, in place)
//   4. k_reorder  : bucket edges by dst -> packed (src, norm) int2
//   5. k_gemm     : xw1 = x @ W1
//   6. k_gather   : h1 = relu(csr_gather + dis^2*xw1 + b1)
//   7. k_gemm     : xw2 = h1 @ W2
//   8. k_gather   : out = csr_gather + dis^2*xw2 + b2
// ---------------------------------------------------------------------------

constexpr int N_NODES = 100000;
constexpr int N_EDGES = 1600000;
constexpr int IN_DIM  = 128;
constexpr int HID_DIM = 128;
constexpr int OUT_DIM = 64;

// --- tiny curvature MLP (16-wide) -------------------------------------------
__device__ __forceinline__ float edge_weight_mlp(float c,
                                                 const float* __restrict__ mw1,
                                                 const float* __restrict__ mb1,
                                                 const float* __restrict__ mw2,
                                                 const float* __restrict__ mb2)
{
    float z = mb2[0];
#pragma unroll
    for (int i = 0; i < 16; ++i) {
        float h = fmaf(c, mw1[i], mb1[i]);
        h = fmaxf(h, 0.0f);
        z = fmaf(h, mw2[i], z);
    }
    float s = 1.0f / (1.0f + __expf(-z));
    return fmaf(0.9f, s, 0.1f);
}

// --- 1. per-edge weight -> weighted degree + in-degree count ----------------
__global__ void k_edge_deg(const float* __restrict__ curv,
                           const int*   __restrict__ dst,
                           const float* __restrict__ mw1,
                           const float* __restrict__ mb1,
                           const float* __restrict__ mw2,
                           const float* __restrict__ mb2,
                           float* __restrict__ deg,
                           int*   __restrict__ cnt)
{
    int e = blockIdx.x * blockDim.x + threadIdx.x;
    if (e >= N_EDGES) return;
    float w = edge_weight_mlp(curv[e], mw1, mb1, mw2, mb2);
    int t = dst[e];
    atomicAdd(&deg[t], w);
    atomicAdd(&cnt[t], 1);
}

// --- 2. dis = rsqrt(deg + 1) -------------------------------------------------
__global__ void k_dis(float* __restrict__ deg_dis)
{
    int n = blockIdx.x * blockDim.x + threadIdx.x;
    if (n >= N_NODES) return;
    deg_dis[n] = rsqrtf(deg_dis[n] + 1.0f);
}

// --- 3. exclusive scan of rp[0..N-1] in place; rp[N] = total -----------------
__global__ void k_scan(int* __restrict__ rp)
{
    __shared__ int part[1024];
    const int t = threadIdx.x;
    const int C = (N_NODES + 1023) / 1024;
    const int lo = t * C;
    const int hi = min(lo + C, N_NODES);
    int s = 0;
    for (int i = lo; i < hi; ++i) s += rp[i];
    part[t] = s;
    __syncthreads();
    for (int ofs = 1; ofs < 1024; ofs <<= 1) {
        int v = (t >= ofs) ? part[t - ofs] : 0;
        __syncthreads();
        part[t] += v;
        __syncthreads();
    }
    int run = (t == 0) ? 0 : part[t - 1];
    for (int i = lo; i < hi; ++i) {
        int v = rp[i];
        rp[i] = run;
        run += v;
    }
    if (lo < N_NODES && hi == N_NODES)
        rp[N_NODES] = run;
}

// --- 4. bucket edges by dst: packed (src, norm) int2 -------------------------
__global__ void k_reorder(const float* __restrict__ curv,
                          const int*   __restrict__ src,
                          const int*   __restrict__ dst,
                          const float* __restrict__ mw1,
                          const float* __restrict__ mb1,
                          const float* __restrict__ mw2,
                          const float* __restrict__ mb2,
                          const float* __restrict__ dis,
                          const int*   __restrict__ rp,
                          int*   __restrict__ wcnt,
                          int2*  __restrict__ ep)
{
    int e = blockIdx.x * blockDim.x + threadIdx.x;
    if (e >= N_EDGES) return;
    float w = edge_weight_mlp(curv[e], mw1, mb1, mw2, mb2);
    int s = src[e], t = dst[e];
    float nm = dis[s] * w * dis[t];
    int pos = rp[t] + atomicAdd(&wcnt[t], 1);
    ep[pos] = make_int2(s, __float_as_int(nm));
}

// --- 5/7. fp32 GEMM: C[N,KOUT] = A[N,KIN] @ W[KIN,KOUT] ----------------------
// 4 rows x float4 cols per thread; k-loop stepped by 4 with float4 A loads:
// 64 FMA per {4 A-float4 + 4 W-float4} loads.
template <int KIN, int KOUT>
__global__ __launch_bounds__(256) void k_gemm(const float* __restrict__ A,
                                              const float* __restrict__ W,
                                              float* __restrict__ C)
{
    constexpr int CQ  = KOUT / 4;            // float4 column groups
    constexpr int RPB = 4 * (256 / CQ);      // rows per block
    const int tid = threadIdx.x;
    const int cq  = tid % CQ;
    const int rg  = tid / CQ;
    const int r0  = blockIdx.x * RPB + 4 * rg;
    if (r0 >= N_NODES) return;               // 4-row granularity, N%4==0
    const float* a0 = A + (size_t)r0 * KIN;
    const float* a1 = a0 + KIN;
    const float* a2 = a1 + KIN;
    const float* a3 = a2 + KIN;
    float4 acc0 = {0,0,0,0}, acc1 = {0,0,0,0}, acc2 = {0,0,0,0}, acc3 = {0,0,0,0};
#pragma unroll 4
    for (int k = 0; k < KIN; k += 4) {
        float4 x0 = *reinterpret_cast<const float4*>(&a0[k]);
        float4 x1 = *reinterpret_cast<const float4*>(&a1[k]);
        float4 x2 = *reinterpret_cast<const float4*>(&a2[k]);
        float4 x3 = *reinterpret_cast<const float4*>(&a3[k]);
        const float* xs0 = &x0.x;
        const float* xs1 = &x1.x;
        const float* xs2 = &x2.x;
        const float* xs3 = &x3.x;
#pragma unroll
        for (int kk = 0; kk < 4; ++kk) {
            float4 w = *reinterpret_cast<const float4*>(&W[(k + kk) * KOUT + 4 * cq]);
            float f0 = xs0[kk], f1 = xs1[kk], f2 = xs2[kk], f3 = xs3[kk];
            acc0.x = fmaf(f0, w.x, acc0.x); acc0.y = fmaf(f0, w.y, acc0.y);
            acc0.z = fmaf(f0, w.z, acc0.z); acc0.w = fmaf(f0, w.w, acc0.w);
            acc1.x = fmaf(f1, w.x, acc1.x); acc1.y = fmaf(f1, w.y, acc1.y);
            acc1.z = fmaf(f1, w.z, acc1.z); acc1.w = fmaf(f1, w.w, acc1.w);
            acc2.x = fmaf(f2, w.x, acc2.x); acc2.y = fmaf(f2, w.y, acc2.y);
            acc2.z = fmaf(f2, w.z, acc2.z); acc2.w = fmaf(f2, w.w, acc2.w);
            acc3.x = fmaf(f3, w.x, acc3.x); acc3.y = fmaf(f3, w.y, acc3.y);
            acc3.z = fmaf(f3, w.z, acc3.z); acc3.w = fmaf(f3, w.w, acc3.w);
        }
    }
    float4* c0 = reinterpret_cast<float4*>(&C[(size_t)r0 * KOUT + 4 * cq]);
    float4* c1 = reinterpret_cast<float4*>(&C[(size_t)(r0 + 1) * KOUT + 4 * cq]);
    float4* c2 = reinterpret_cast<float4*>(&C[(size_t)(r0 + 2) * KOUT + 4 * cq]);
    float4* c3 = reinterpret_cast<float4*>(&C[(size_t)(r0 + 3) * KOUT + 4 * cq]);
    *c0 = acc0; *c1 = acc1; *c2 = acc2; *c3 = acc3;
}

// --- 6/8. CSR gather with fused finalize, 4-way edge unroll ------------------
// NPB nodes per 256-thread block; thread handles one (node, dim) element.
// Edge records are packed int2 (broadcast loads); 4 independent row-gathers
// in flight per thread.
template <int DIM, bool RELU>
__global__ __launch_bounds__(256) void k_gather(const int*  __restrict__ rp,
                                                const int2* __restrict__ ep,
                                                const float* __restrict__ xw,
                                                const float* __restrict__ dis,
                                                const float* __restrict__ bias,
                                                float* __restrict__ out)
{
    constexpr int NPB = 256 / DIM;
    const int tid = threadIdx.x;
    const int n   = blockIdx.x * NPB + tid / DIM;   // N_NODES % NPB == 0
    const int d   = tid % DIM;
    const int beg = rp[n];
    const int end = rp[n + 1];

    float a0 = 0.f, a1 = 0.f, a2 = 0.f, a3 = 0.f;
    int i = beg;
    for (; i + 4 <= end; i += 4) {
        int2 e0 = ep[i], e1 = ep[i + 1], e2 = ep[i + 2], e3 = ep[i + 3];
        float v0 = xw[(size_t)e0.x * DIM + d];
        float v1 = xw[(size_t)e1.x * DIM + d];
        float v2 = xw[(size_t)e2.x * DIM + d];
        float v3 = xw[(size_t)e3.x * DIM + d];
        a0 = fmaf(__int_as_float(e0.y), v0, a0);
        a1 = fmaf(__int_as_float(e1.y), v1, a1);
        a2 = fmaf(__int_as_float(e2.y), v2, a2);
        a3 = fmaf(__int_as_float(e3.y), v3, a3);
    }
    for (; i < end; ++i) {
        int2 e = ep[i];
        a0 = fmaf(__int_as_float(e.y), xw[(size_t)e.x * DIM + d], a0);
    }
    float acc = (a0 + a1) + (a2 + a3);
    float di = dis[n];
    float v  = fmaf(di * di, xw[(size_t)n * DIM + d], acc) + bias[d];
    if (RELU) v = fmaxf(v, 0.0f);
    out[(size_t)n * DIM + d] = v;
}

extern "C" void kernel_launch(void* const* d_in, const int* in_sizes, int n_in,
                              void* d_out, int out_size, void* d_ws, size_t ws_size,
                              hipStream_t stream)
{
    const float* x    = (const float*)d_in[0];
    const int*   eidx = (const int*)  d_in[1];   // [2, N_EDGES] int32
    const float* curv = (const float*)d_in[2];   // [N_EDGES, 1]
    const float* W1   = (const float*)d_in[3];
    const float* b1   = (const float*)d_in[4];
    const float* W2   = (const float*)d_in[5];
    const float* b2   = (const float*)d_in[6];
    const float* mw1  = (const float*)d_in[7];
    const float* mb1  = (const float*)d_in[8];
    const float* mw2  = (const float*)d_in[9];
    const float* mb2  = (const float*)d_in[10];

    const int* src = eidx;
    const int* dst = eidx + N_EDGES;
    float* out = (float*)d_out;

    // --- workspace carve-out (~123 MB) ---
    char*  ws  = (char*)d_ws;
    size_t off = 0;
    auto alloc = [&](size_t bytes) -> void* {
        void* p = ws + off;
        off += (bytes + 255) & ~(size_t)255;
        return p;
    };
    float* deg  = (float*)alloc(sizeof(float) * N_NODES);                     // -> dis in place
    int*   rp   = (int*)  alloc(sizeof(int) * (N_NODES + 1));                 // counts -> rowptr
    int*   wcnt = (int*)  alloc(sizeof(int) * N_NODES);                       // bucket cursors
    int2*  ep   = (int2*) alloc(sizeof(int2) * N_EDGES);                      // packed (src,norm)
    float* xw   = (float*)alloc(sizeof(float) * (size_t)N_NODES * HID_DIM);   // xw1, then xw2
    float* h1   = (float*)alloc(sizeof(float) * (size_t)N_NODES * HID_DIM);

    hipMemsetAsync(deg,  0, sizeof(float) * N_NODES, stream);
    hipMemsetAsync(rp,   0, sizeof(int) * N_NODES, stream);
    hipMemsetAsync(wcnt, 0, sizeof(int) * N_NODES, stream);

    const int B = 256;
    auto cdiv = [](long long a, long long b) { return (int)((a + b - 1) / b); };

    // CSR build
    k_edge_deg<<<cdiv(N_EDGES, B), B, 0, stream>>>(curv, dst, mw1, mb1, mw2, mb2, deg, rp);
    k_dis     <<<cdiv(N_NODES, B), B, 0, stream>>>(deg);
    k_scan    <<<1, 1024, 0, stream>>>(rp);
    k_reorder <<<cdiv(N_EDGES, B), B, 0, stream>>>(curv, src, dst, mw1, mb1, mw2, mb2,
                                                   deg, rp, wcnt, ep);

    // layer 1
    k_gemm<IN_DIM, HID_DIM><<<N_NODES / 32, 256, 0, stream>>>(x, W1, xw);
    k_gather<HID_DIM, true><<<N_NODES / 2, 256, 0, stream>>>(rp, ep, xw, deg, b1, h1);

    // layer 2
    k_gemm<HID_DIM, OUT_DIM><<<cdiv(N_NODES, 64), 256, 0, stream>>>(h1, W2, xw);
    k_gather<OUT_DIM, false><<<N_NODES / 4, 256, 0, stream>>>(rp, ep, xw, deg, b2, out);
}

// Round 6
// 603.202 us; speedup vs baseline: 2.8758x; 1.2644x over previous
//
#include <hip/hip_runtime.h>

// ---------------------------------------------------------------------------
// LearnableCurvGCN, round 5: kill the single-block scan (164us -> ~15us).
//
// R4 counters: k_scan was the top dispatch at 164us, OccupancyPercent 0.16,
// 3.6 GB/s — one block serially walking 100K counts. Replaced with a 3-phase
// device-wide scan (196-block partial reduce -> 1-block scan of partials ->
// 196-block in-chunk scan). Also: edge MLP computed once (stored ew, aliased
// onto the h1 buffer), single fused memset.
//
// Pipeline:
//   1. k_edge_deg   : per-edge MLP -> ew[e]; atomicAdd(deg[dst],w), cnt[dst]++
//   2. k_dis        : dis = rsqrt(deg+1)              (in place over deg)
//   3. k_scan_part  : bsum[b] = sum of cnt chunk b
//      k_scan_mid   : bsum = exclusive_scan(bsum); rp[N] = total
//      k_scan_final : rp chunk b = exclusive in-chunk scan + bsum[b]
//   4. k_reorder    : bucket edges by dst -> packed (src, norm) int2
//   5. k_gemm       : xw1 = x @ W1       (4 rows x float4 cols / thread)
//   6. k_gather     : h1 = relu(csr_gather + dis^2*xw1 + b1)
//   7. k_gemm       : xw2 = h1 @ W2
//   8. k_gather     : out = csr_gather + dis^2*xw2 + b2
// ---------------------------------------------------------------------------

constexpr int N_NODES = 100000;
constexpr int N_EDGES = 1600000;
constexpr int IN_DIM  = 128;
constexpr int HID_DIM = 128;
constexpr int OUT_DIM = 64;

constexpr int SCAN_CHUNK = 512;                                   // nodes per scan block
constexpr int SCAN_NB    = (N_NODES + SCAN_CHUNK - 1) / SCAN_CHUNK; // 196

// --- tiny curvature MLP (16-wide) -------------------------------------------
__device__ __forceinline__ float edge_weight_mlp(float c,
                                                 const float* __restrict__ mw1,
                                                 const float* __restrict__ mb1,
                                                 const float* __restrict__ mw2,
                                                 const float* __restrict__ mb2)
{
    float z = mb2[0];
#pragma unroll
    for (int i = 0; i < 16; ++i) {
        float h = fmaf(c, mw1[i], mb1[i]);
        h = fmaxf(h, 0.0f);
        z = fmaf(h, mw2[i], z);
    }
    float s = 1.0f / (1.0f + __expf(-z));
    return fmaf(0.9f, s, 0.1f);
}

// --- 1. per-edge weight (stored) + weighted degree + in-degree count --------
__global__ void k_edge_deg(const float* __restrict__ curv,
                           const int*   __restrict__ dst,
                           const float* __restrict__ mw1,
                           const float* __restrict__ mb1,
                           const float* __restrict__ mw2,
                           const float* __restrict__ mb2,
                           float* __restrict__ ew,
                           float* __restrict__ deg,
                           int*   __restrict__ cnt)
{
    int e = blockIdx.x * blockDim.x + threadIdx.x;
    if (e >= N_EDGES) return;
    float w = edge_weight_mlp(curv[e], mw1, mb1, mw2, mb2);
    ew[e] = w;
    int t = dst[e];
    atomicAdd(&deg[t], w);
    atomicAdd(&cnt[t], 1);
}

// --- 2. dis = rsqrt(deg + 1) -------------------------------------------------
__global__ void k_dis(float* __restrict__ deg_dis)
{
    int n = blockIdx.x * blockDim.x + threadIdx.x;
    if (n >= N_NODES) return;
    deg_dis[n] = rsqrtf(deg_dis[n] + 1.0f);
}

// --- 3a. per-chunk reduce: bsum[b] = sum(cnt[b*512 .. b*512+511]) ------------
__global__ __launch_bounds__(256) void k_scan_part(const int* __restrict__ cnt,
                                                   int* __restrict__ bsum)
{
    const int b = blockIdx.x;
    const int t = threadIdx.x;
    const int i = b * SCAN_CHUNK + 2 * t;
    int s = 0;
    if (i < N_NODES)     s += cnt[i];
    if (i + 1 < N_NODES) s += cnt[i + 1];
#pragma unroll
    for (int o = 32; o > 0; o >>= 1) s += __shfl_down(s, o, 64);
    __shared__ int ws[4];
    if ((t & 63) == 0) ws[t >> 6] = s;
    __syncthreads();
    if (t == 0) bsum[b] = ws[0] + ws[1] + ws[2] + ws[3];
}

// --- 3b. scan the 196 partials (one small block); rp[N] = total --------------
__global__ __launch_bounds__(256) void k_scan_mid(int* __restrict__ bsum,
                                                  int* __restrict__ rp)
{
    const int t = threadIdx.x;
    int v = (t < SCAN_NB) ? bsum[t] : 0;
    __shared__ int sm[256];
    sm[t] = v;
    __syncthreads();
#pragma unroll
    for (int o = 1; o < 256; o <<= 1) {
        int u = (t >= o) ? sm[t - o] : 0;
        __syncthreads();
        sm[t] += u;
        __syncthreads();
    }
    if (t < SCAN_NB) bsum[t] = sm[t] - v;       // exclusive
    if (t == SCAN_NB - 1) rp[N_NODES] = sm[t];  // grand total
}

// --- 3c. in-chunk exclusive scan + chunk offset (in place over counts) -------
__global__ __launch_bounds__(256) void k_scan_final(int* __restrict__ rp,
                                                    const int* __restrict__ bsum)
{
    const int b = blockIdx.x;
    const int t = threadIdx.x;
    const int i = b * SCAN_CHUNK + 2 * t;
    int c0 = (i < N_NODES)     ? rp[i]     : 0;
    int c1 = (i + 1 < N_NODES) ? rp[i + 1] : 0;
    int s = c0 + c1;
    __shared__ int sm[256];
    sm[t] = s;
    __syncthreads();
#pragma unroll
    for (int o = 1; o < 256; o <<= 1) {
        int u = (t >= o) ? sm[t - o] : 0;
        __syncthreads();
        sm[t] += u;
        __syncthreads();
    }
    int excl = sm[t] - s + bsum[b];
    if (i < N_NODES)     rp[i]     = excl;
    if (i + 1 < N_NODES) rp[i + 1] = excl + c0;
}

// --- 4. bucket edges by dst: packed (src, norm) int2 -------------------------
__global__ void k_reorder(const float* __restrict__ ew,
                          const int*   __restrict__ src,
                          const int*   __restrict__ dst,
                          const float* __restrict__ dis,
                          const int*   __restrict__ rp,
                          int*   __restrict__ wcnt,
                          int2*  __restrict__ ep)
{
    int e = blockIdx.x * blockDim.x + threadIdx.x;
    if (e >= N_EDGES) return;
    int s = src[e], t = dst[e];
    float nm = dis[s] * ew[e] * dis[t];
    int pos = rp[t] + atomicAdd(&wcnt[t], 1);
    ep[pos] = make_int2(s, __float_as_int(nm));
}

// --- 5/7. fp32 GEMM: C[N,KOUT] = A[N,KIN] @ W[KIN,KOUT] ----------------------
template <int KIN, int KOUT>
__global__ __launch_bounds__(256) void k_gemm(const float* __restrict__ A,
                                              const float* __restrict__ W,
                                              float* __restrict__ C)
{
    constexpr int CQ  = KOUT / 4;
    constexpr int RPB = 4 * (256 / CQ);
    const int tid = threadIdx.x;
    const int cq  = tid % CQ;
    const int rg  = tid / CQ;
    const int r0  = blockIdx.x * RPB + 4 * rg;
    if (r0 >= N_NODES) return;               // 4-row granularity, N%4==0
    const float* a0 = A + (size_t)r0 * KIN;
    const float* a1 = a0 + KIN;
    const float* a2 = a1 + KIN;
    const float* a3 = a2 + KIN;
    float4 acc0 = {0,0,0,0}, acc1 = {0,0,0,0}, acc2 = {0,0,0,0}, acc3 = {0,0,0,0};
#pragma unroll 4
    for (int k = 0; k < KIN; k += 4) {
        float4 x0 = *reinterpret_cast<const float4*>(&a0[k]);
        float4 x1 = *reinterpret_cast<const float4*>(&a1[k]);
        float4 x2 = *reinterpret_cast<const float4*>(&a2[k]);
        float4 x3 = *reinterpret_cast<const float4*>(&a3[k]);
        const float* xs0 = &x0.x;
        const float* xs1 = &x1.x;
        const float* xs2 = &x2.x;
        const float* xs3 = &x3.x;
#pragma unroll
        for (int kk = 0; kk < 4; ++kk) {
            float4 w = *reinterpret_cast<const float4*>(&W[(k + kk) * KOUT + 4 * cq]);
            float f0 = xs0[kk], f1 = xs1[kk], f2 = xs2[kk], f3 = xs3[kk];
            acc0.x = fmaf(f0, w.x, acc0.x); acc0.y = fmaf(f0, w.y, acc0.y);
            acc0.z = fmaf(f0, w.z, acc0.z); acc0.w = fmaf(f0, w.w, acc0.w);
            acc1.x = fmaf(f1, w.x, acc1.x); acc1.y = fmaf(f1, w.y, acc1.y);
            acc1.z = fmaf(f1, w.z, acc1.z); acc1.w = fmaf(f1, w.w, acc1.w);
            acc2.x = fmaf(f2, w.x, acc2.x); acc2.y = fmaf(f2, w.y, acc2.y);
            acc2.z = fmaf(f2, w.z, acc2.z); acc2.w = fmaf(f2, w.w, acc2.w);
            acc3.x = fmaf(f3, w.x, acc3.x); acc3.y = fmaf(f3, w.y, acc3.y);
            acc3.z = fmaf(f3, w.z, acc3.z); acc3.w = fmaf(f3, w.w, acc3.w);
        }
    }
    *reinterpret_cast<float4*>(&C[(size_t)r0 * KOUT + 4 * cq])       = acc0;
    *reinterpret_cast<float4*>(&C[(size_t)(r0 + 1) * KOUT + 4 * cq]) = acc1;
    *reinterpret_cast<float4*>(&C[(size_t)(r0 + 2) * KOUT + 4 * cq]) = acc2;
    *reinterpret_cast<float4*>(&C[(size_t)(r0 + 3) * KOUT + 4 * cq]) = acc3;
}

// --- 6/8. CSR gather with fused finalize, 4-way edge unroll ------------------
template <int DIM, bool RELU>
__global__ __launch_bounds__(256) void k_gather(const int*  __restrict__ rp,
                                                const int2* __restrict__ ep,
                                                const float* __restrict__ xw,
                                                const float* __restrict__ dis,
                                                const float* __restrict__ bias,
                                                float* __restrict__ out)
{
    constexpr int NPB = 256 / DIM;
    const int tid = threadIdx.x;
    const int n   = blockIdx.x * NPB + tid / DIM;   // N_NODES % NPB == 0
    const int d   = tid % DIM;
    const int beg = rp[n];
    const int end = rp[n + 1];

    float a0 = 0.f, a1 = 0.f, a2 = 0.f, a3 = 0.f;
    int i = beg;
    for (; i + 4 <= end; i += 4) {
        int2 e0 = ep[i], e1 = ep[i + 1], e2 = ep[i + 2], e3 = ep[i + 3];
        float v0 = xw[(size_t)e0.x * DIM + d];
        float v1 = xw[(size_t)e1.x * DIM + d];
        float v2 = xw[(size_t)e2.x * DIM + d];
        float v3 = xw[(size_t)e3.x * DIM + d];
        a0 = fmaf(__int_as_float(e0.y), v0, a0);
        a1 = fmaf(__int_as_float(e1.y), v1, a1);
        a2 = fmaf(__int_as_float(e2.y), v2, a2);
        a3 = fmaf(__int_as_float(e3.y), v3, a3);
    }
    for (; i < end; ++i) {
        int2 e = ep[i];
        a0 = fmaf(__int_as_float(e.y), xw[(size_t)e.x * DIM + d], a0);
    }
    float acc = (a0 + a1) + (a2 + a3);
    float di = dis[n];
    float v  = fmaf(di * di, xw[(size_t)n * DIM + d], acc) + bias[d];
    if (RELU) v = fmaxf(v, 0.0f);
    out[(size_t)n * DIM + d] = v;
}

extern "C" void kernel_launch(void* const* d_in, const int* in_sizes, int n_in,
                              void* d_out, int out_size, void* d_ws, size_t ws_size,
                              hipStream_t stream)
{
    const float* x    = (const float*)d_in[0];
    const int*   eidx = (const int*)  d_in[1];   // [2, N_EDGES] int32
    const float* curv = (const float*)d_in[2];   // [N_EDGES, 1]
    const float* W1   = (const float*)d_in[3];
    const float* b1   = (const float*)d_in[4];
    const float* W2   = (const float*)d_in[5];
    const float* b2   = (const float*)d_in[6];
    const float* mw1  = (const float*)d_in[7];
    const float* mb1  = (const float*)d_in[8];
    const float* mw2  = (const float*)d_in[9];
    const float* mb2  = (const float*)d_in[10];

    const int* src = eidx;
    const int* dst = eidx + N_EDGES;
    float* out = (float*)d_out;

    // --- workspace carve-out (~123 MB) ---
    char*  ws  = (char*)d_ws;
    size_t off = 0;
    auto alloc = [&](size_t bytes) -> void* {
        void* p = ws + off;
        off += (bytes + 255) & ~(size_t)255;
        return p;
    };
    float* deg  = (float*)alloc(sizeof(float) * N_NODES);                     // -> dis in place
    int*   rp   = (int*)  alloc(sizeof(int) * (N_NODES + 1));                 // counts -> rowptr
    int*   wcnt = (int*)  alloc(sizeof(int) * N_NODES);                       // bucket cursors
    int*   bsum = (int*)  alloc(sizeof(int) * 256);                           // scan partials
    int2*  ep   = (int2*) alloc(sizeof(int2) * N_EDGES);                      // packed (src,norm)
    float* xw   = (float*)alloc(sizeof(float) * (size_t)N_NODES * HID_DIM);   // xw1, then xw2
    float* h1   = (float*)alloc(sizeof(float) * (size_t)N_NODES * HID_DIM);
    // ew aliases h1: ew is only live between k_edge_deg and k_reorder, long
    // before the first k_gather writes h1.
    float* ewbuf = h1;

    // one fused memset over the contiguous deg|rp|wcnt region
    size_t zs = (size_t)((char*)bsum - (char*)deg);
    hipMemsetAsync(deg, 0, zs, stream);

    const int B = 256;
    auto cdiv = [](long long a, long long b) { return (int)((a + b - 1) / b); };

    // CSR build
    k_edge_deg  <<<cdiv(N_EDGES, B), B, 0, stream>>>(curv, dst, mw1, mb1, mw2, mb2,
                                                     ewbuf, deg, rp);
    k_dis       <<<cdiv(N_NODES, B), B, 0, stream>>>(deg);
    k_scan_part <<<SCAN_NB, 256, 0, stream>>>(rp, bsum);
    k_scan_mid  <<<1, 256, 0, stream>>>(bsum, rp);
    k_scan_final<<<SCAN_NB, 256, 0, stream>>>(rp, bsum);
    k_reorder   <<<cdiv(N_EDGES, B), B, 0, stream>>>(ewbuf, src, dst, deg, rp, wcnt, ep);

    // layer 1
    k_gemm<IN_DIM, HID_DIM><<<N_NODES / 32, 256, 0, stream>>>(x, W1, xw);
    k_gather<HID_DIM, true><<<N_NODES / 2, 256, 0, stream>>>(rp, ep, xw, deg, b1, h1);

    // layer 2
    k_gemm<HID_DIM, OUT_DIM><<<cdiv(N_NODES, 64), 256, 0, stream>>>(h1, W2, xw);
    k_gather<OUT_DIM, false><<<N_NODES / 4, 256, 0, stream>>>(rp, ep, xw, deg, b2, out);
}

// Round 7
// 560.257 us; speedup vs baseline: 3.0962x; 1.0767x over previous
//
#include <hip/hip_runtime.h>

// ---------------------------------------------------------------------------
// LearnableCurvGCN, round 6: kill atomic contention + raise gather MLP.
//
// R5 counters: k_edge_deg 142us @ VALUBusy 2.6% (3.2M atomics over 200K
// addresses, ~16 serialized hits each, 32B HBM write per RMW) and
// k_gather<128> 142us @ 41% HBM / 32% VALU (not enough loads in flight).
//
// Changes:
//   - deg float atomics ELIMINATED: reorder (src, ew) into CSR first, then
//     deg = per-node segment sum, dis = rsqrt(deg+1), then flat coalesced
//     norm pass using nd[] (node-of-position, written by reorder).
//   - count histogram uses 4 replicas (blockIdx&3) -> contention /4;
//     replicas summed inside the scan phases.
//   - gather: float2 per thread + 8-wide edge unroll -> 8 independent 8B
//     gathers in flight per thread.
//
// Pipeline:
//   1. k_edge_cnt   : cnt4[rep][dst]++                      (only atomics: 1/edge)
//   2. k_scan_part/mid/final : rp = exclusive_scan(sum cnt4)
//   3. k_reorder    : MLP(curv) -> ew; pos = rp[dst]+wcnt[dst]++;
//                     ep[pos]=(src,ew); nd[pos]=dst
//   4. k_deg_dis    : dis[n] = rsqrt(sum_bucket(ew) + 1)    (no atomics)
//   5. k_norm       : ep[i].y = dis[src]*ew*dis[nd[i]]      (flat, coalesced)
//   6. k_gemm       : xw1 = x @ W1
//   7. k_gather     : h1 = relu(csr_gather + dis^2*xw1 + b1)
//   8. k_gemm       : xw2 = h1 @ W2
//   9. k_gather     : out = csr_gather + dis^2*xw2 + b2
// ---------------------------------------------------------------------------

constexpr int N_NODES = 100000;
constexpr int N_EDGES = 1600000;
constexpr int IN_DIM  = 128;
constexpr int HID_DIM = 128;
constexpr int OUT_DIM = 64;
constexpr int NREP    = 4;     // count-histogram replicas

constexpr int SCAN_CHUNK = 512;
constexpr int SCAN_NB    = (N_NODES + SCAN_CHUNK - 1) / SCAN_CHUNK; // 196

// --- tiny curvature MLP (16-wide) -------------------------------------------
__device__ __forceinline__ float edge_weight_mlp(float c,
                                                 const float* __restrict__ mw1,
                                                 const float* __restrict__ mb1,
                                                 const float* __restrict__ mw2,
                                                 const float* __restrict__ mb2)
{
    float z = mb2[0];
#pragma unroll
    for (int i = 0; i < 16; ++i) {
        float h = fmaf(c, mw1[i], mb1[i]);
        h = fmaxf(h, 0.0f);
        z = fmaf(h, mw2[i], z);
    }
    float s = 1.0f / (1.0f + __expf(-z));
    return fmaf(0.9f, s, 0.1f);
}

// --- 1. replicated in-degree histogram ---------------------------------------
__global__ void k_edge_cnt(const int* __restrict__ dst,
                           int* __restrict__ cnt4)
{
    int e = blockIdx.x * blockDim.x + threadIdx.x;
    if (e >= N_EDGES) return;
    atomicAdd(&cnt4[(blockIdx.x & (NREP - 1)) * N_NODES + dst[e]], 1);
}

// --- 2a. per-chunk reduce over replica-summed counts --------------------------
__global__ __launch_bounds__(256) void k_scan_part(const int* __restrict__ cnt4,
                                                   int* __restrict__ bsum)
{
    const int b = blockIdx.x;
    const int t = threadIdx.x;
    const int i = b * SCAN_CHUNK + 2 * t;
    int s = 0;
#pragma unroll
    for (int r = 0; r < NREP; ++r) {
        if (i < N_NODES)     s += cnt4[r * N_NODES + i];
        if (i + 1 < N_NODES) s += cnt4[r * N_NODES + i + 1];
    }
#pragma unroll
    for (int o = 32; o > 0; o >>= 1) s += __shfl_down(s, o, 64);
    __shared__ int ws[4];
    if ((t & 63) == 0) ws[t >> 6] = s;
    __syncthreads();
    if (t == 0) bsum[b] = ws[0] + ws[1] + ws[2] + ws[3];
}

// --- 2b. scan the 196 partials; rp[N] = total ---------------------------------
__global__ __launch_bounds__(256) void k_scan_mid(int* __restrict__ bsum,
                                                  int* __restrict__ rp)
{
    const int t = threadIdx.x;
    int v = (t < SCAN_NB) ? bsum[t] : 0;
    __shared__ int sm[256];
    sm[t] = v;
    __syncthreads();
#pragma unroll
    for (int o = 1; o < 256; o <<= 1) {
        int u = (t >= o) ? sm[t - o] : 0;
        __syncthreads();
        sm[t] += u;
        __syncthreads();
    }
    if (t < SCAN_NB) bsum[t] = sm[t] - v;
    if (t == SCAN_NB - 1) rp[N_NODES] = sm[t];
}

// --- 2c. in-chunk exclusive scan + chunk offset -> rp -------------------------
__global__ __launch_bounds__(256) void k_scan_final(const int* __restrict__ cnt4,
                                                    int* __restrict__ rp,
                                                    const int* __restrict__ bsum)
{
    const int b = blockIdx.x;
    const int t = threadIdx.x;
    const int i = b * SCAN_CHUNK + 2 * t;
    int c0 = 0, c1 = 0;
#pragma unroll
    for (int r = 0; r < NREP; ++r) {
        if (i < N_NODES)     c0 += cnt4[r * N_NODES + i];
        if (i + 1 < N_NODES) c1 += cnt4[r * N_NODES + i + 1];
    }
    int s = c0 + c1;
    __shared__ int sm[256];
    sm[t] = s;
    __syncthreads();
#pragma unroll
    for (int o = 1; o < 256; o <<= 1) {
        int u = (t >= o) ? sm[t - o] : 0;
        __syncthreads();
        sm[t] += u;
        __syncthreads();
    }
    int excl = sm[t] - s + bsum[b];
    if (i < N_NODES)     rp[i]     = excl;
    if (i + 1 < N_NODES) rp[i + 1] = excl + c0;
}

// --- 3. bucket edges by dst: ep=(src, ew), nd=dst -----------------------------
__global__ void k_reorder(const float* __restrict__ curv,
                          const int*   __restrict__ src,
                          const int*   __restrict__ dst,
                          const float* __restrict__ mw1,
                          const float* __restrict__ mb1,
                          const float* __restrict__ mw2,
                          const float* __restrict__ mb2,
                          const int*   __restrict__ rp,
                          int*   __restrict__ wcnt,
                          int2*  __restrict__ ep,
                          int*   __restrict__ nd)
{
    int e = blockIdx.x * blockDim.x + threadIdx.x;
    if (e >= N_EDGES) return;
    float w = edge_weight_mlp(curv[e], mw1, mb1, mw2, mb2);
    int s = src[e], t = dst[e];
    int pos = rp[t] + atomicAdd(&wcnt[t], 1);
    ep[pos] = make_int2(s, __float_as_int(w));
    nd[pos] = t;
}

// --- 4. dis[n] = rsqrt(segment_sum(ew) + 1) -----------------------------------
__global__ void k_deg_dis(const int*  __restrict__ rp,
                          const int2* __restrict__ ep,
                          float* __restrict__ dis)
{
    int n = blockIdx.x * blockDim.x + threadIdx.x;
    if (n >= N_NODES) return;
    int beg = rp[n], end = rp[n + 1];
    float s = 0.0f;
    for (int i = beg; i < end; ++i)
        s += __int_as_float(ep[i].y);
    dis[n] = rsqrtf(s + 1.0f);
}

// --- 5. norm pass: ep[i].y = dis[src]*ew*dis[node] (flat, coalesced) ----------
__global__ void k_norm(const int* __restrict__ nd,
                       const float* __restrict__ dis,
                       int2* __restrict__ ep)
{
    int i = blockIdx.x * blockDim.x + threadIdx.x;
    if (i >= N_EDGES) return;
    int2 e = ep[i];
    float nm = dis[e.x] * __int_as_float(e.y) * dis[nd[i]];
    ep[i] = make_int2(e.x, __float_as_int(nm));
}

// --- 6/8. fp32 GEMM: C[N,KOUT] = A[N,KIN] @ W[KIN,KOUT] -----------------------
template <int KIN, int KOUT>
__global__ __launch_bounds__(256) void k_gemm(const float* __restrict__ A,
                                              const float* __restrict__ W,
                                              float* __restrict__ C)
{
    constexpr int CQ  = KOUT / 4;
    constexpr int RPB = 4 * (256 / CQ);
    const int tid = threadIdx.x;
    const int cq  = tid % CQ;
    const int rg  = tid / CQ;
    const int r0  = blockIdx.x * RPB + 4 * rg;
    if (r0 >= N_NODES) return;               // 4-row granularity, N%4==0
    const float* a0 = A + (size_t)r0 * KIN;
    const float* a1 = a0 + KIN;
    const float* a2 = a1 + KIN;
    const float* a3 = a2 + KIN;
    float4 acc0 = {0,0,0,0}, acc1 = {0,0,0,0}, acc2 = {0,0,0,0}, acc3 = {0,0,0,0};
#pragma unroll 4
    for (int k = 0; k < KIN; k += 4) {
        float4 x0 = *reinterpret_cast<const float4*>(&a0[k]);
        float4 x1 = *reinterpret_cast<const float4*>(&a1[k]);
        float4 x2 = *reinterpret_cast<const float4*>(&a2[k]);
        float4 x3 = *reinterpret_cast<const float4*>(&a3[k]);
        const float* xs0 = &x0.x;
        const float* xs1 = &x1.x;
        const float* xs2 = &x2.x;
        const float* xs3 = &x3.x;
#pragma unroll
        for (int kk = 0; kk < 4; ++kk) {
            float4 w = *reinterpret_cast<const float4*>(&W[(k + kk) * KOUT + 4 * cq]);
            float f0 = xs0[kk], f1 = xs1[kk], f2 = xs2[kk], f3 = xs3[kk];
            acc0.x = fmaf(f0, w.x, acc0.x); acc0.y = fmaf(f0, w.y, acc0.y);
            acc0.z = fmaf(f0, w.z, acc0.z); acc0.w = fmaf(f0, w.w, acc0.w);
            acc1.x = fmaf(f1, w.x, acc1.x); acc1.y = fmaf(f1, w.y, acc1.y);
            acc1.z = fmaf(f1, w.z, acc1.z); acc1.w = fmaf(f1, w.w, acc1.w);
            acc2.x = fmaf(f2, w.x, acc2.x); acc2.y = fmaf(f2, w.y, acc2.y);
            acc2.z = fmaf(f2, w.z, acc2.z); acc2.w = fmaf(f2, w.w, acc2.w);
            acc3.x = fmaf(f3, w.x, acc3.x); acc3.y = fmaf(f3, w.y, acc3.y);
            acc3.z = fmaf(f3, w.z, acc3.z); acc3.w = fmaf(f3, w.w, acc3.w);
        }
    }
    *reinterpret_cast<float4*>(&C[(size_t)r0 * KOUT + 4 * cq])       = acc0;
    *reinterpret_cast<float4*>(&C[(size_t)(r0 + 1) * KOUT + 4 * cq]) = acc1;
    *reinterpret_cast<float4*>(&C[(size_t)(r0 + 2) * KOUT + 4 * cq]) = acc2;
    *reinterpret_cast<float4*>(&C[(size_t)(r0 + 3) * KOUT + 4 * cq]) = acc3;
}

// --- 7/9. CSR gather, float2/thread, 8-wide edge unroll, fused finalize -------
template <int DIM, bool RELU>
__global__ __launch_bounds__(256) void k_gather(const int*  __restrict__ rp,
                                                const int2* __restrict__ ep,
                                                const float* __restrict__ xw,
                                                const float* __restrict__ dis,
                                                const float* __restrict__ bias,
                                                float* __restrict__ out)
{
    constexpr int TPN = DIM / 2;          // threads per node
    constexpr int NPB = 256 / TPN;        // nodes per block (N_NODES % NPB == 0)
    const int tid = threadIdx.x;
    const int n   = blockIdx.x * NPB + tid / TPN;
    const int d2  = tid % TPN;
    const float2* xw2 = reinterpret_cast<const float2*>(xw);
    const int beg = rp[n];
    const int end = rp[n + 1];

    float2 a0{0,0}, a1{0,0}, a2{0,0}, a3{0,0};
    int i = beg;
    for (; i + 8 <= end; i += 8) {
        int2 e0 = ep[i],     e1 = ep[i + 1], e2 = ep[i + 2], e3 = ep[i + 3];
        int2 e4 = ep[i + 4], e5 = ep[i + 5], e6 = ep[i + 6], e7 = ep[i + 7];
        float2 v0 = xw2[(size_t)e0.x * TPN + d2];
        float2 v1 = xw2[(size_t)e1.x * TPN + d2];
        float2 v2 = xw2[(size_t)e2.x * TPN + d2];
        float2 v3 = xw2[(size_t)e3.x * TPN + d2];
        float2 v4 = xw2[(size_t)e4.x * TPN + d2];
        float2 v5 = xw2[(size_t)e5.x * TPN + d2];
        float2 v6 = xw2[(size_t)e6.x * TPN + d2];
        float2 v7 = xw2[(size_t)e7.x * TPN + d2];
        float w0 = __int_as_float(e0.y), w1 = __int_as_float(e1.y);
        float w2 = __int_as_float(e2.y), w3 = __int_as_float(e3.y);
        float w4 = __int_as_float(e4.y), w5 = __int_as_float(e5.y);
        float w6 = __int_as_float(e6.y), w7 = __int_as_float(e7.y);
        a0.x = fmaf(w0, v0.x, a0.x); a0.y = fmaf(w0, v0.y, a0.y);
        a1.x = fmaf(w1, v1.x, a1.x); a1.y = fmaf(w1, v1.y, a1.y);
        a2.x = fmaf(w2, v2.x, a2.x); a2.y = fmaf(w2, v2.y, a2.y);
        a3.x = fmaf(w3, v3.x, a3.x); a3.y = fmaf(w3, v3.y, a3.y);
        a0.x = fmaf(w4, v4.x, a0.x); a0.y = fmaf(w4, v4.y, a0.y);
        a1.x = fmaf(w5, v5.x, a1.x); a1.y = fmaf(w5, v5.y, a1.y);
        a2.x = fmaf(w6, v6.x, a2.x); a2.y = fmaf(w6, v6.y, a2.y);
        a3.x = fmaf(w7, v7.x, a3.x); a3.y = fmaf(w7, v7.y, a3.y);
    }
    for (; i + 2 <= end; i += 2) {
        int2 e0 = ep[i], e1 = ep[i + 1];
        float2 v0 = xw2[(size_t)e0.x * TPN + d2];
        float2 v1 = xw2[(size_t)e1.x * TPN + d2];
        float w0 = __int_as_float(e0.y), w1 = __int_as_float(e1.y);
        a0.x = fmaf(w0, v0.x, a0.x); a0.y = fmaf(w0, v0.y, a0.y);
        a1.x = fmaf(w1, v1.x, a1.x); a1.y = fmaf(w1, v1.y, a1.y);
    }
    if (i < end) {
        int2 e0 = ep[i];
        float2 v0 = xw2[(size_t)e0.x * TPN + d2];
        float w0 = __int_as_float(e0.y);
        a0.x = fmaf(w0, v0.x, a0.x); a0.y = fmaf(w0, v0.y, a0.y);
    }
    float accx = (a0.x + a1.x) + (a2.x + a3.x);
    float accy = (a0.y + a1.y) + (a2.y + a3.y);

    float di = dis[n];
    float s2 = di * di;
    float2 xn = xw2[(size_t)n * TPN + d2];
    float2 bb = reinterpret_cast<const float2*>(bias)[d2];
    float vx = fmaf(s2, xn.x, accx) + bb.x;
    float vy = fmaf(s2, xn.y, accy) + bb.y;
    if (RELU) { vx = fmaxf(vx, 0.0f); vy = fmaxf(vy, 0.0f); }
    reinterpret_cast<float2*>(out)[(size_t)n * TPN + d2] = make_float2(vx, vy);
}

extern "C" void kernel_launch(void* const* d_in, const int* in_sizes, int n_in,
                              void* d_out, int out_size, void* d_ws, size_t ws_size,
                              hipStream_t stream)
{
    const float* x    = (const float*)d_in[0];
    const int*   eidx = (const int*)  d_in[1];   // [2, N_EDGES] int32
    const float* curv = (const float*)d_in[2];   // [N_EDGES, 1]
    const float* W1   = (const float*)d_in[3];
    const float* b1   = (const float*)d_in[4];
    const float* W2   = (const float*)d_in[5];
    const float* b2   = (const float*)d_in[6];
    const float* mw1  = (const float*)d_in[7];
    const float* mb1  = (const float*)d_in[8];
    const float* mw2  = (const float*)d_in[9];
    const float* mb2  = (const float*)d_in[10];

    const int* src = eidx;
    const int* dst = eidx + N_EDGES;
    float* out = (float*)d_out;

    // --- workspace carve-out (~125 MB) ---
    char*  ws  = (char*)d_ws;
    size_t off = 0;
    auto alloc = [&](size_t bytes) -> void* {
        void* p = ws + off;
        off += (bytes + 255) & ~(size_t)255;
        return p;
    };
    float* dis  = (float*)alloc(sizeof(float) * N_NODES);
    int*   rp   = (int*)  alloc(sizeof(int) * (N_NODES + 1));
    int*   wcnt = (int*)  alloc(sizeof(int) * N_NODES);            // [zeroed]
    int*   cnt4 = (int*)  alloc(sizeof(int) * NREP * N_NODES);     // [zeroed]
    int*   bsum = (int*)  alloc(sizeof(int) * 256);
    int*   nd   = (int*)  alloc(sizeof(int) * N_EDGES);            // node-of-position
    int2*  ep   = (int2*) alloc(sizeof(int2) * N_EDGES);           // (src, ew->norm)
    float* xw   = (float*)alloc(sizeof(float) * (size_t)N_NODES * HID_DIM);
    float* h1   = (float*)alloc(sizeof(float) * (size_t)N_NODES * HID_DIM);

    // one fused memset over the contiguous wcnt|cnt4 region (~2 MB)
    hipMemsetAsync(wcnt, 0, (size_t)((char*)bsum - (char*)wcnt), stream);

    const int B = 256;
    auto cdiv = [](long long a, long long b) { return (int)((a + b - 1) / b); };

    // CSR build (no float atomics anywhere)
    k_edge_cnt  <<<cdiv(N_EDGES, B), B, 0, stream>>>(dst, cnt4);
    k_scan_part <<<SCAN_NB, 256, 0, stream>>>(cnt4, bsum);
    k_scan_mid  <<<1, 256, 0, stream>>>(bsum, rp);
    k_scan_final<<<SCAN_NB, 256, 0, stream>>>(cnt4, rp, bsum);
    k_reorder   <<<cdiv(N_EDGES, B), B, 0, stream>>>(curv, src, dst, mw1, mb1, mw2, mb2,
                                                     rp, wcnt, ep, nd);
    k_deg_dis   <<<cdiv(N_NODES, B), B, 0, stream>>>(rp, ep, dis);
    k_norm      <<<cdiv(N_EDGES, B), B, 0, stream>>>(nd, dis, ep);

    // layer 1
    k_gemm<IN_DIM, HID_DIM><<<N_NODES / 32, 256, 0, stream>>>(x, W1, xw);
    k_gather<HID_DIM, true><<<N_NODES / 4, 256, 0, stream>>>(rp, ep, xw, dis, b1, h1);

    // layer 2
    k_gemm<HID_DIM, OUT_DIM><<<cdiv(N_NODES, 64), 256, 0, stream>>>(h1, W2, xw);
    k_gather<OUT_DIM, false><<<N_NODES / 8, 256, 0, stream>>>(rp, ep, xw, dis, b2, out);
}